// Round 1
// baseline (1090.568 us; speedup 1.0000x reference)
//
#include <hip/hip_runtime.h>

// PMField: B=131072 particles, C=256 centers, D=64 dims, 8 steps.
// One thread per particle; z[64] and g[64] live in VGPRs across all 8 steps.
// Centers read with wave-uniform index from global (s_load / K$-cache
// candidate); cn2 and mus staged in LDS once per block.
// __launch_bounds__(256,2): cap 256 VGPR -> 2 waves/SIMD, 512 blocks = 2/CU.

#define B_TOT 131072
#define C_N   256
#define D_N   64
#define STEPS 8
#define DTB   0.15f    // DT * BETA
#define EPSF  1e-4f

__launch_bounds__(256, 2)
__global__ void pmfield_kernel(const float* __restrict__ z_in,
                               const float* __restrict__ centers,
                               const float* __restrict__ mus,
                               float* __restrict__ z_out) {
    __shared__ float s_cn2[C_N];
    __shared__ float s_mu[C_N];

    const int tid = threadIdx.x;

    // One-time per block: |c|^2 per center (thread t -> center t), and mus.
    {
        const float* cr = centers + tid * D_N;
        float a0 = 0.f, a1 = 0.f, a2 = 0.f, a3 = 0.f;
#pragma unroll
        for (int d = 0; d < D_N; d += 4) {
            a0 += cr[d]     * cr[d];
            a1 += cr[d + 1] * cr[d + 1];
            a2 += cr[d + 2] * cr[d + 2];
            a3 += cr[d + 3] * cr[d + 3];
        }
        s_cn2[tid] = (a0 + a1) + (a2 + a3);
        s_mu[tid]  = mus[tid];
    }
    __syncthreads();

    const int pid = blockIdx.x * 256 + tid;
    const float* zp = z_in + (size_t)pid * D_N;

    float z[D_N];
#pragma unroll
    for (int d = 0; d < D_N; d += 4) {
        float4 v = *(const float4*)(zp + d);
        z[d] = v.x; z[d + 1] = v.y; z[d + 2] = v.z; z[d + 3] = v.w;
    }

    for (int s = 0; s < STEPS; ++s) {
        // zz = |z|^2
        float zz0 = 0.f, zz1 = 0.f, zz2 = 0.f, zz3 = 0.f;
#pragma unroll
        for (int d = 0; d < D_N; d += 4) {
            zz0 += z[d]     * z[d];
            zz1 += z[d + 1] * z[d + 1];
            zz2 += z[d + 2] * z[d + 2];
            zz3 += z[d + 3] * z[d + 3];
        }
        const float zz = (zz0 + zz1) + (zz2 + zz3);

        float g[D_N];
#pragma unroll
        for (int d = 0; d < D_N; ++d) g[d] = 0.f;

        float nacc = 0.f;   // sum_c mu/r
        float sw   = 0.f;   // sum_c w

        for (int c = 0; c < C_N; ++c) {
            const float* cr = centers + c * D_N;   // wave-uniform address

            // Load the center row once; reused for dot and for g-accumulate.
            float crow[D_N];
#pragma unroll
            for (int d = 0; d < D_N; d += 4) {
                float4 v = *(const float4*)(cr + d);
                crow[d] = v.x; crow[d + 1] = v.y;
                crow[d + 2] = v.z; crow[d + 3] = v.w;
            }

            float d0 = 0.f, d1 = 0.f, d2 = 0.f, d3 = 0.f;
#pragma unroll
            for (int d = 0; d < D_N; d += 4) {
                d0 += z[d]     * crow[d];
                d1 += z[d + 1] * crow[d + 1];
                d2 += z[d + 2] * crow[d + 2];
                d3 += z[d + 3] * crow[d + 3];
            }
            const float dot = (d0 + d1) + (d2 + d3);

            const float r2 = fmaxf(zz + s_cn2[c] - 2.0f * dot, 0.0f) + EPSF;
            const float r  = sqrtf(r2);
            const float w  = s_mu[c] / (r2 * r);   // mu / r^3
            nacc += w * r2;                        // == mu / r
            sw   += w;

#pragma unroll
            for (int d = 0; d < D_N; ++d) g[d] += w * crow[d];
        }

        const float n    = 1.0f + nacc;
        const float ninv = 1.0f / n;
#pragma unroll
        for (int d = 0; d < D_N; ++d) {
            const float gd = (g[d] - z[d] * sw) * ninv;
            const float zn = z[d] + DTB * gd;
            z[d] = fminf(fmaxf(zn, -3.0f), 3.0f);
        }
    }

    float* op = z_out + (size_t)pid * D_N;
#pragma unroll
    for (int d = 0; d < D_N; d += 4) {
        *(float4*)(op + d) = make_float4(z[d], z[d + 1], z[d + 2], z[d + 3]);
    }
}

extern "C" void kernel_launch(void* const* d_in, const int* in_sizes, int n_in,
                              void* d_out, int out_size, void* d_ws, size_t ws_size,
                              hipStream_t stream) {
    const float* z       = (const float*)d_in[0];
    const float* centers = (const float*)d_in[1];
    const float* mus     = (const float*)d_in[2];
    float* out           = (float*)d_out;

    dim3 grid(B_TOT / 256);
    dim3 block(256);
    pmfield_kernel<<<grid, block, 0, stream>>>(z, centers, mus, out);
}